// Round 1
// 324.451 us; speedup vs baseline: 1.0431x; 1.0431x over previous
//
#include <hip/hip_runtime.h>
#include <hip/hip_bf16.h>

// ModulatedConv2d: B=8, Cin=Cout=512, K=3, H=W=64, pad=1, groups=B.
// bf16 MFMA implicit GEMM per batch: C[512,4096] = Wmod[512,4608] x Im2col.
// R8: conv_gemm moved from the 2-barrier m97 structure (vmcnt(0) drain per
// K-step, ~860 TF) to the 256x256 8-phase schedule (T2+T3+T4+T5):
//   - 8 waves (512 thr, 2Mx4N), BK=64, 16x16x32 MFMA, per-wave C = 128x64
//   - LDS = ring of 4 half-tile slots per matrix (128 KiB total); tiles
//     advance 2/iter so slot indices are compile-time constants
//   - per phase: ds_read subtile | stage 1 half-tile (2x global_load_lds,
//     width 16) | raw s_barrier | lgkmcnt(0) | setprio(1) 16 MFMA setprio(0)
//     | s_barrier.  s_waitcnt vmcnt(6) ONLY at phases 4 and 8 (3 half-tiles
//     stay in flight across barriers; never drained to 0 in the main loop).
//   - chunk swizzle c ^= (row&7) (8 chunks/row), linear LDS dest +
//     pre-swizzled global source; ds_read un-swizzles. 0 bank conflicts.
// modw_k: parallelized over b (grid 512x8); weight re-reads are L3-resident.

#define CIN   512
#define COUT  512
#define KDIM  4608        // 9 * 512
#define HWPIX 4096

typedef __attribute__((ext_vector_type(8))) __bf16 bf16x8;
typedef __attribute__((ext_vector_type(4))) float  f32x4;

__device__ __forceinline__ unsigned short f2bf(float f){
  union { float f; unsigned int u; } v; v.f = f;
  unsigned int u = v.u;
  u += 0x7fffu + ((u >> 16) & 1u);     // round-to-nearest-even
  return (unsigned short)(u >> 16);
}

#define GLDS16(g, l) __builtin_amdgcn_global_load_lds(                      \
    (const __attribute__((address_space(1))) unsigned int*)(g),             \
    (__attribute__((address_space(3))) unsigned int*)(l), 16, 0, 0)

// ---------------- styles: s[b][c] = dot(w[b], affine_w[c]) + ab[c] + 1 ----
__global__ void style_k(const float* __restrict__ w, const float* __restrict__ aw,
                        const float* __restrict__ ab, float* __restrict__ styles){
  int wid = threadIdx.x >> 6, lane = threadIdx.x & 63;
  int gid = blockIdx.x * 4 + wid;           // 0..4095 = b*512 + c
  int b = gid >> 9, c = gid & 511;
  const float* wb = w + b * 512;
  const float* ar = aw + c * 512;
  float sum = 0.f;
  for (int j = lane; j < 512; j += 64) sum += wb[j] * ar[j];
  for (int off = 32; off; off >>= 1) sum += __shfl_down(sum, off, 64);
  if (lane == 0) styles[gid] = sum + ab[c] + 1.0f;
}

// ------------- modulate + demodulate -> bf16 wmod[b][o][tap*512+cin] ------
// One block per (o, b); weight row re-read 8x but L3-resident (9.4 MB).
__global__ void modw_k(const float* __restrict__ weight, const float* __restrict__ styles,
                       unsigned short* __restrict__ wmod){
  int o = blockIdx.x;                  // 0..511
  int b = blockIdx.y;                  // 0..7
  int t = threadIdx.x;
  const float* wrow = weight + (size_t)o * KDIM;   // weight[0][o][i][ky][kx]
  const float* st = styles + b * 512;
  __shared__ unsigned short sw[9 * 520];           // tap stride 520 (pad vs 512)
  __shared__ float red[4];
  int wid = t >> 6, lane = t & 63;
  float vals[18];
  float part = 0.f;
#pragma unroll
  for (int it = 0; it < 18; ++it){
    int idx = it * 256 + t;
    int i = idx / 9;
    float v = wrow[idx] * st[i];
    vals[it] = v;
    part += v * v;
  }
  for (int off = 32; off; off >>= 1) part += __shfl_down(part, off, 64);
  if (lane == 0) red[wid] = part;
  __syncthreads();
  float d = rsqrtf(red[0] + red[1] + red[2] + red[3] + 1e-8f);
#pragma unroll
  for (int it = 0; it < 18; ++it){
    int idx = it * 256 + t;
    int i = idx / 9;
    int tap = idx - i * 9;
    sw[tap * 520 + i] = f2bf(vals[it] * d);
  }
  __syncthreads();
  unsigned int* orow32 = (unsigned int*)(wmod + ((size_t)(b * 512 + o)) * KDIM);
#pragma unroll
  for (int it = 0; it < 9; ++it){     // 2304 dwords, fully coalesced
    int u = it * 256 + t;
    int e = u * 2;
    int tap2 = e >> 9, i2 = e & 511;
    orow32[u] = *(const unsigned int*)&sw[tap2 * 520 + i2];
  }
}

// ----- transpose+pad: x[b][c][h][w] fp32 -> xpad[b][h+1][w+1][c] bf16 -----
__global__ void xpose_k(const float* __restrict__ x, unsigned short* __restrict__ xpad){
  int h = blockIdx.x, cg = blockIdx.y, b = blockIdx.z;
  int c0 = cg * 64;
  __shared__ unsigned short lds[64][66];   // [w][c]: writes 2-way (free), reads clean
  int t = threadIdx.x;
  const float* xb = x + (((size_t)(b * 512 + c0)) * 64 + h) * 64;
#pragma unroll
  for (int it = 0; it < 16; ++it){
    int idx = it * 256 + t;
    int cl = idx >> 6, wl = idx & 63;     // cl wave-uniform, wl = lane
    lds[wl][cl] = f2bf(xb[(size_t)cl * 4096 + wl]);
  }
  if (t < 64){
    int which = t >> 5;                   // 0: w=0, 1: w=65
    int ch2 = (t & 31) * 2;
    int wl = which ? 65 : 0;
    *(unsigned int*)&xpad[(((size_t)b * 66 + h + 1) * 66 + wl) * 512 + c0 + ch2] = 0u;
  }
  if (h == 0 || h == 63){                 // rows 0 / 65, all 66 w
    int row = (h == 0) ? 0 : 65;
    for (int u = t; u < 66 * 32; u += 256){
      int wl = u >> 5, ch2 = (u & 31) * 2;
      *(unsigned int*)&xpad[(((size_t)b * 66 + row) * 66 + wl) * 512 + c0 + ch2] = 0u;
    }
  }
  __syncthreads();
#pragma unroll
  for (int it = 0; it < 2; ++it){
    int idx = it * 256 + t;
    int wl = idx >> 3, ch = idx & 7;
    unsigned int u0 = *(const unsigned int*)&lds[wl][ch * 8 + 0];
    unsigned int u1 = *(const unsigned int*)&lds[wl][ch * 8 + 2];
    unsigned int u2 = *(const unsigned int*)&lds[wl][ch * 8 + 4];
    unsigned int u3 = *(const unsigned int*)&lds[wl][ch * 8 + 6];
    int off = ((b * 66 + h + 1) * 66 + (wl + 1)) * 512 + c0 + ch * 8;
    *(uint4*)&xpad[off] = make_uint4(u0, u1, u2, u3);
  }
}

// --------------------------- main conv GEMM ------------------------------
// per-tile scalar shift into xpad for tap (dy,dx) and channel slice of K-step t
__device__ __forceinline__ int bshift_of(int t){
  int tap = t >> 3;
  int dy = (tap * 11) >> 5;              // tap/3 for tap in [0,9)
  int dx = tap - dy * 3;
  return (((dy - 1) * 66 + (dx - 1)) << 9) + ((t & 7) << 6);
}

__global__ __launch_bounds__(512, 2) void conv_gemm(
    const unsigned short* __restrict__ wmod, const unsigned short* __restrict__ xpad,
    const float* __restrict__ noise, const float* __restrict__ bias,
    float* __restrict__ out){
  // ring of 4 half-tile slots per matrix; half = 128 rows x 64 k = 16 KiB
  __shared__ unsigned short As[4][128 * 64];   // 64 KiB
  __shared__ unsigned short Bs[4][128 * 64];   // 64 KiB
  int g = blockIdx.x;                          // 256 blocks: 1 per CU
  int b = g & 7, sl = g >> 3;                  // b == XCD
  int mt = sl >> 4, nt = sl & 15;
  int m0 = mt * 256, n0 = nt * 256, h0 = nt * 4;  // 4 image rows per n-tile
  int tid = threadIdx.x, lane = tid & 63, wid = tid >> 6;
  int wmp = wid >> 2, wnp = wid & 3;           // 2M x 4N waves within a quadrant
  int lf = lane & 15, lg = lane >> 4;

  const unsigned short* wbase = wmod + ((size_t)(b * 512 + m0)) * KDIM;
  const unsigned short* xb    = xpad + (size_t)b * (66 * 66 * 512);

  // staging: u = i*512+tid -> row u>>3 (of 128), LDS chunk u&7; fetch global
  // chunk (u&7)^(row&7) so linear LDS holds the swizzled layout.
  int srow  = tid >> 3;                        // 0..63 (call 2 adds +64: same &7)
  int sc    = (tid & 7) ^ (srow & 7);
  int aoffg  = srow * KDIM + sc * 8;
  int boffg0 = ((h0 + 1) * 66 + srow + 1) * 512 + sc * 8;
  int boffg1 = ((h0 + 2) * 66 + srow + 1) * 512 + sc * 8;

  // frag reads: row r = base + lf (r&7 == lane&7), logical chunk kh*4+lg,
  // physical chunk = logical ^ (lane&7)
  int arow[4], brow[2];
#pragma unroll
  for (int i = 0; i < 4; ++i) arow[i] = (wmp * 64 + i * 16 + lf) * 64;
#pragma unroll
  for (int j = 0; j < 2; ++j) brow[j] = (wnp * 32 + j * 16 + lf) * 64;
  int pch0 = ((lg    ) ^ (lane & 7)) * 8;
  int pch1 = ((lg + 4) ^ (lane & 7)) * 8;

  f32x4 acc[2][2][4][2];
#pragma unroll
  for (int a0 = 0; a0 < 2; ++a0)
#pragma unroll
    for (int a1 = 0; a1 < 2; ++a1)
#pragma unroll
      for (int a2 = 0; a2 < 4; ++a2)
#pragma unroll
        for (int a3 = 0; a3 < 2; ++a3) acc[a0][a1][a2][a3] = (f32x4){0.f, 0.f, 0.f, 0.f};

  bf16x8 af[4][2], bq0[2][2], bq1[2][2];

#define STAGE_A(t_, h_, s_) do {                                              \
    const unsigned short* gpa_ = wbase + (size_t)(h_) * (128 * KDIM) + (t_) * 64; \
    GLDS16(gpa_ + aoffg,             &As[s_][tid * 8]);                       \
    GLDS16(gpa_ + aoffg + 64 * KDIM, &As[s_][(512 + tid) * 8]);               \
  } while (0)

#define STAGE_B(t_, h_, s_) do {                                              \
    const unsigned short* gpb_ = xb + (h_) * (2 * 66 * 512) + bshift_of(t_);  \
    GLDS16(gpb_ + boffg0, &Bs[s_][tid * 8]);                                  \
    GLDS16(gpb_ + boffg1, &Bs[s_][(512 + tid) * 8]);                          \
  } while (0)

#define LOAD_A(s_) do {                                                       \
    _Pragma("unroll") for (int fi_ = 0; fi_ < 4; ++fi_){                      \
      af[fi_][0] = *(const bf16x8*)&As[s_][arow[fi_] + pch0];                 \
      af[fi_][1] = *(const bf16x8*)&As[s_][arow[fi_] + pch1]; }               \
  } while (0)

#define LOAD_B(s_, B_) do {                                                   \
    _Pragma("unroll") for (int fj_ = 0; fj_ < 2; ++fj_){                      \
      B_[fj_][0] = *(const bf16x8*)&Bs[s_][brow[fj_] + pch0];                 \
      B_[fj_][1] = *(const bf16x8*)&Bs[s_][brow[fj_] + pch1]; }               \
  } while (0)

#define MFMA_Q(MH_, NH_, B_) do {                                             \
    __builtin_amdgcn_s_setprio(1);                                            \
    _Pragma("unroll") for (int fi_ = 0; fi_ < 4; ++fi_)                       \
    _Pragma("unroll") for (int fj_ = 0; fj_ < 2; ++fj_){                      \
      acc[MH_][NH_][fi_][fj_] = __builtin_amdgcn_mfma_f32_16x16x32_bf16(      \
          af[fi_][0], B_[fj_][0], acc[MH_][NH_][fi_][fj_], 0, 0, 0);          \
      acc[MH_][NH_][fi_][fj_] = __builtin_amdgcn_mfma_f32_16x16x32_bf16(      \
          af[fi_][1], B_[fj_][1], acc[MH_][NH_][fi_][fj_], 0, 0, 0); }        \
    __builtin_amdgcn_s_setprio(0);                                            \
  } while (0)

#define SYNC_MID() do { __builtin_amdgcn_s_barrier();                         \
    asm volatile("s_waitcnt lgkmcnt(0)"); } while (0)
#define SYNC_END() __builtin_amdgcn_s_barrier()
#define VMW6() asm volatile("s_waitcnt vmcnt(6)" ::: "memory")
#define VMW0() asm volatile("s_waitcnt vmcnt(0)" ::: "memory")

  // prologue: tile0 (slots A0,B0,B1,A1 -> 0,0,1,1) then tile1 partial.
  // vmcnt(6) leaves last 3 half-tiles {A0(1),B0(1),B1(1)} in flight.
  STAGE_A(0, 0, 0); STAGE_B(0, 0, 0); STAGE_B(0, 1, 1); STAGE_A(0, 1, 1);
  STAGE_A(1, 0, 2); STAGE_B(1, 0, 2); STAGE_B(1, 1, 3);
  VMW6();
  __builtin_amdgcn_s_barrier();

  // main loop: iteration computes tiles T=2i (slots 0/1), T+1 (slots 2/3);
  // stages A1(T+1)@P1, tile T+2@P2-P5, tile T+3 (A0,B0,B1)@P6-P8.
#pragma unroll 1
  for (int it = 0; it < 35; ++it){
    int T = it * 2;
    // P1: quadrant (M0,N0) of T
    LOAD_A(0); LOAD_B(0, bq0);
    STAGE_A(T + 1, 1, 3);
    SYNC_MID(); MFMA_Q(0, 0, bq0); SYNC_END();
    // P2: (M0,N1)
    LOAD_B(1, bq1);
    STAGE_A(T + 2, 0, 0);            // A-slot0 last read P1
    SYNC_MID(); MFMA_Q(0, 1, bq1); SYNC_END();
    // P3: (M1,N0)
    LOAD_A(1);
    STAGE_B(T + 2, 0, 0);            // B-slot0 last read P1
    SYNC_MID(); MFMA_Q(1, 0, bq0); SYNC_END();
    // P4: (M1,N1); retire tile T+1 (keep 3 half-tiles in flight)
    STAGE_B(T + 2, 1, 1);            // B-slot1 last read P2
    VMW6();
    SYNC_MID(); MFMA_Q(1, 1, bq1); SYNC_END();
    // P5: quadrant (M0,N0) of T+1
    LOAD_A(2); LOAD_B(2, bq0);
    STAGE_A(T + 2, 1, 1);            // A-slot1 last read P3
    SYNC_MID(); MFMA_Q(0, 0, bq0); SYNC_END();
    // P6: (M0,N1)
    LOAD_B(3, bq1);
    STAGE_A(T + 3, 0, 2);            // A-slot2 last read P5
    SYNC_MID(); MFMA_Q(0, 1, bq1); SYNC_END();
    // P7: (M1,N0)
    LOAD_A(3);
    STAGE_B(T + 3, 0, 2);            // B-slot2 last read P5
    SYNC_MID(); MFMA_Q(1, 0, bq0); SYNC_END();
    // P8: (M1,N1); retire tile T+2
    STAGE_B(T + 3, 1, 3);            // B-slot3 last read P6
    VMW6();
    SYNC_MID(); MFMA_Q(1, 1, bq1); SYNC_END();
  }

  // epilogue iteration: tiles 70 (slots 0/1), 71 (slots 2/3); only A1(71)
  // remains to stage; vmcnt(0) at P4 drains everything.
  LOAD_A(0); LOAD_B(0, bq0);
  STAGE_A(71, 1, 3);
  SYNC_MID(); MFMA_Q(0, 0, bq0); SYNC_END();
  LOAD_B(1, bq1);
  SYNC_MID(); MFMA_Q(0, 1, bq1); SYNC_END();
  LOAD_A(1);
  SYNC_MID(); MFMA_Q(1, 0, bq0); SYNC_END();
  VMW0();
  SYNC_MID(); MFMA_Q(1, 1, bq1); SYNC_END();
  LOAD_A(2); LOAD_B(2, bq0);
  SYNC_MID(); MFMA_Q(0, 0, bq0); SYNC_END();
  LOAD_B(3, bq1);
  SYNC_MID(); MFMA_Q(0, 1, bq1); SYNC_END();
  LOAD_A(3);
  SYNC_MID(); MFMA_Q(1, 0, bq0); SYNC_END();
  SYNC_MID(); MFMA_Q(1, 1, bq1);

#undef STAGE_A
#undef STAGE_B
#undef LOAD_A
#undef LOAD_B
#undef MFMA_Q
#undef SYNC_MID
#undef SYNC_END
#undef VMW6
#undef VMW0

  // epilogue: + noise + bias, leaky relu 0.2. C/D map: row=(lane>>4)*4+reg,
  // col=lane&15
#pragma unroll
  for (int MH = 0; MH < 2; ++MH)
#pragma unroll
    for (int NH = 0; NH < 2; ++NH)
#pragma unroll
      for (int fi = 0; fi < 4; ++fi)
#pragma unroll
        for (int fj = 0; fj < 2; ++fj){
          int o_base = m0 + MH * 128 + wmp * 64 + fi * 16 + lg * 4;
          int n = n0 + NH * 128 + wnp * 32 + fj * 16 + lf;
#pragma unroll
          for (int r = 0; r < 4; ++r){
            int o = o_base + r;
            size_t idx = ((size_t)(b * 512 + o)) * HWPIX + n;
            float v = acc[MH][NH][fi][fj][r] + noise[idx] + bias[o];
            out[idx] = (v >= 0.f) ? v : 0.2f * v;
          }
        }
}

extern "C" void kernel_launch(void* const* d_in, const int* in_sizes, int n_in,
                              void* d_out, int out_size, void* d_ws, size_t ws_size,
                              hipStream_t stream) {
  const float* x        = (const float*)d_in[0];
  const float* w        = (const float*)d_in[1];
  const float* noise    = (const float*)d_in[2];
  const float* weight   = (const float*)d_in[3];
  const float* affine_w = (const float*)d_in[4];
  const float* affine_b = (const float*)d_in[5];
  const float* bias     = (const float*)d_in[6];
  float* out = (float*)d_out;

  // workspace: styles 16KB | wmod 37,748,736B | xpad 35,684,352B  (~73.5 MB)
  float* styles = (float*)d_ws;
  unsigned short* wmod = (unsigned short*)((char*)d_ws + 16384);
  unsigned short* xpad = (unsigned short*)((char*)d_ws + 16384 + 37748736ull);

  style_k<<<dim3(1024), 256, 0, stream>>>(w, affine_w, affine_b, styles);
  modw_k <<<dim3(512, 8), 256, 0, stream>>>(weight, styles, wmod);
  xpose_k<<<dim3(64, 8, 8), 256, 0, stream>>>(x, xpad);
  conv_gemm<<<dim3(256), 512, 0, stream>>>(wmod, xpad, noise, bias, out);
}